// Round 1
// baseline (738.212 us; speedup 1.0000x reference)
//
#include <hip/hip_runtime.h>

typedef unsigned short u16;
using floatx4 = __attribute__((ext_vector_type(4))) float;
using short8  = __attribute__((ext_vector_type(8))) short;

__device__ __forceinline__ u16 f2bf(float f){
  unsigned int u = __float_as_uint(f);
  u += 0x7fffu + ((u >> 16) & 1u);   // round-to-nearest-even
  return (u16)(u >> 16);
}

// ---------------------------------------------------------------------------
// rowsum: dinv[row] = d!=0 ? rsqrt(sum_j |L[row][j]|) : 0      (402 MB read)
// rows 0..4095 -> L0, 4096..12287 -> L1, 12288..16383 -> L2
// ---------------------------------------------------------------------------
__global__ __launch_bounds__(256) void rowsum_kernel(
    const float* __restrict__ L0, const float* __restrict__ L1,
    const float* __restrict__ L2, float* __restrict__ dinv)
{
  int row = blockIdx.x;
  const float* L; int N; int lrow;
  if (row < 4096)       { L = L0; N = 4096; lrow = row; }
  else if (row < 12288) { L = L1; N = 8192; lrow = row - 4096; }
  else                  { L = L2; N = 4096; lrow = row - 12288; }
  const float4* p = (const float4*)(L + (size_t)lrow * N);
  float s = 0.f;
  int n4 = N >> 2;
  for (int i = threadIdx.x; i < n4; i += 256){
    float4 v = p[i];
    s += fabsf(v.x) + fabsf(v.y) + fabsf(v.z) + fabsf(v.w);
  }
  #pragma unroll
  for (int off = 32; off > 0; off >>= 1) s += __shfl_down(s, off);
  __shared__ float wsum[4];
  if ((threadIdx.x & 63) == 0) wsum[threadIdx.x >> 6] = s;
  __syncthreads();
  if (threadIdx.x == 0){
    float d = wsum[0] + wsum[1] + wsum[2] + wsum[3];
    dinv[row] = (d != 0.f) ? rsqrtf(d) : 0.f;
  }
}

// ---------------------------------------------------------------------------
// xw: Yst[c][j] = bf16( dinv[j] * (x @ W_layer)[j][c] )  -- TRANSPOSED output
// so the big GEMM's B-operand fragments are contiguous along k.
// One block = 64 rows of one rank. MFMA 16x16x32 on LDS-staged bf16 tiles.
// ---------------------------------------------------------------------------
__global__ __launch_bounds__(256) void xw_kernel(
    const float* __restrict__ x0, const float* __restrict__ x1,
    const float* __restrict__ x2, const float* __restrict__ xbuf,
    const float* __restrict__ W0c, const float* __restrict__ W1c,
    const float* __restrict__ W2c, int layer,
    const float* __restrict__ dinv,
    u16* __restrict__ yst0, u16* __restrict__ yst1, u16* __restrict__ yst2)
{
  int grow0 = blockIdx.x * 64;         // global row base (0..16383)
  int lrow0, N; const float* xin; const float* W; u16* yst;
  if (grow0 < 4096)       { lrow0 = grow0;         N = 4096; W = W0c; yst = yst0; xin = x0; }
  else if (grow0 < 12288) { lrow0 = grow0 - 4096;  N = 8192; W = W1c; yst = yst1; xin = x1; }
  else                    { lrow0 = grow0 - 12288; N = 4096; W = W2c; yst = yst2; xin = x2; }
  const float* xsrc = layer ? (xbuf + (size_t)grow0 * 64) : (xin + (size_t)lrow0 * 64);
  W += layer * 4096;

  // bf16 tiles, stride 72 (pad) -> ds_read_b128 of fragments is 2-way (free)
  __shared__ u16 xt[64 * 72];   // xt[j][k]
  __shared__ u16 wt[64 * 72];   // wt[c][k] = W[k][c] (transposed)

  int tid = threadIdx.x;
  {
    int j  = tid >> 2;
    int c0 = (tid & 3) * 16;
    const float* src = xsrc + j * 64 + c0;
    #pragma unroll
    for (int i = 0; i < 4; i++){
      float4 v = *(const float4*)(src + i * 4);
      int o = j * 72 + c0 + i * 4;
      xt[o + 0] = f2bf(v.x); xt[o + 1] = f2bf(v.y);
      xt[o + 2] = f2bf(v.z); xt[o + 3] = f2bf(v.w);
    }
    const float* wsrc = W + j * 64 + c0;   // j doubles as k-index for W staging
    #pragma unroll
    for (int i = 0; i < 4; i++){
      float4 v = *(const float4*)(wsrc + i * 4);
      int c = c0 + i * 4;
      wt[(c + 0) * 72 + j] = f2bf(v.x);
      wt[(c + 1) * 72 + j] = f2bf(v.y);
      wt[(c + 2) * 72 + j] = f2bf(v.z);
      wt[(c + 3) * 72 + j] = f2bf(v.w);
    }
  }
  __syncthreads();

  int lane = tid & 63, w = tid >> 6;
  int m = lane & 15, q = lane >> 4;
  floatx4 acc[4] = {};
  #pragma unroll
  for (int kk = 0; kk < 2; kk++){
    short8 af = *(const short8*)(&xt[(w * 16 + m) * 72 + kk * 32 + q * 8]);
    #pragma unroll
    for (int ct = 0; ct < 4; ct++){
      short8 bf = *(const short8*)(&wt[(ct * 16 + m) * 72 + kk * 32 + q * 8]);
      acc[ct] = __builtin_amdgcn_mfma_f32_16x16x32_bf16(af, bf, acc[ct], 0, 0, 0);
    }
  }
  // C layout: row(j) = q*4+r (+w*16), col(c) = m (+ct*16)   [m89-verified]
  #pragma unroll
  for (int r = 0; r < 4; r++){
    int j = w * 16 + q * 4 + r;
    float di = dinv[grow0 + j];
    #pragma unroll
    for (int ct = 0; ct < 4; ct++){
      int c = ct * 16 + m;
      yst[(size_t)c * N + lrow0 + j] = f2bf(acc[ct][r] * di);
    }
  }
}

// ---------------------------------------------------------------------------
// Big GEMM: part[h][i][c] (+)= sum_{k in range} L[i][k] * Yst[c][k]
// 512 blocks: rank0 [0,128), rank1 [128,384), rank2 [384,512).
// Block = (mblock, khalf h): 64 rows x 64 cols; 4 waves split the K-half 4-way,
// LDS-reduce, write one fp32 partial. A loaded global->reg (fp32, cvt to bf16).
// ---------------------------------------------------------------------------
struct AStage { float4 v[4][2]; };   // [rowtile][16B half] : 8 floats/lane
struct BStage { short8 b[4]; };      // [coltile]

__device__ __forceinline__ void loadA(AStage& s, const float* __restrict__ L,
                                      const int aoff[4], int k){
  #pragma unroll
  for (int rt = 0; rt < 4; rt++){
    const float4* p = (const float4*)(L + aoff[rt] + k);
    s.v[rt][0] = p[0];
    s.v[rt][1] = p[1];
  }
}
__device__ __forceinline__ void loadB(BStage& s, const u16* __restrict__ yst,
                                      const int boff[4], int k){
  #pragma unroll
  for (int ct = 0; ct < 4; ct++)
    s.b[ct] = *(const short8*)(yst + boff[ct] + k);
}
__device__ __forceinline__ void consume(const AStage& a, const BStage& b,
                                        floatx4 acc[4][4]){
  #pragma unroll
  for (int rt = 0; rt < 4; rt++){
    union { short8 s8; unsigned int u[4]; } cv;
    float4 lo = a.v[rt][0], hi = a.v[rt][1];
    cv.u[0] = (unsigned)f2bf(lo.x) | ((unsigned)f2bf(lo.y) << 16);
    cv.u[1] = (unsigned)f2bf(lo.z) | ((unsigned)f2bf(lo.w) << 16);
    cv.u[2] = (unsigned)f2bf(hi.x) | ((unsigned)f2bf(hi.y) << 16);
    cv.u[3] = (unsigned)f2bf(hi.z) | ((unsigned)f2bf(hi.w) << 16);
    #pragma unroll
    for (int ct = 0; ct < 4; ct++)
      acc[rt][ct] = __builtin_amdgcn_mfma_f32_16x16x32_bf16(cv.s8, b.b[ct],
                                                            acc[rt][ct], 0, 0, 0);
  }
}

__global__ __launch_bounds__(256, 2) void gemm_kernel(
    const float* __restrict__ L0, const float* __restrict__ L1,
    const float* __restrict__ L2,
    const u16* __restrict__ yst0, const u16* __restrict__ yst1,
    const u16* __restrict__ yst2, float* __restrict__ part)
{
  int b = blockIdx.x;
  const float* L; const u16* yst; int N, growoff, mb, h;
  if (b < 128)      { L = L0; yst = yst0; N = 4096; growoff = 0;     mb = b >> 1;          h = b & 1; }
  else if (b < 384) { L = L1; yst = yst1; N = 8192; growoff = 4096;  mb = (b - 128) >> 1;  h = b & 1; }
  else              { L = L2; yst = yst2; N = 4096; growoff = 12288; mb = (b - 384) >> 1;  h = b & 1; }
  int m0 = mb * 64;
  int tid = threadIdx.x, lane = tid & 63, w = tid >> 6;
  int m = lane & 15, q = lane >> 4;
  int kstart = h * (N >> 1) + w * (N >> 3);
  int chunks = N >> 8;               // per-wave chunks of 32 (16 or 32, always even)

  int aoff[4], boff[4];
  #pragma unroll
  for (int rt = 0; rt < 4; rt++) aoff[rt] = (m0 + rt * 16 + m) * N + q * 8;
  #pragma unroll
  for (int ct = 0; ct < 4; ct++) boff[ct] = (ct * 16 + m) * N + q * 8;

  floatx4 acc[4][4] = {};
  int k = kstart;
  AStage a0, a1; BStage b0, b1;
  loadA(a0, L, aoff, k); loadB(b0, yst, boff, k);
  for (int c = 0; c < chunks; c += 2){
    loadA(a1, L, aoff, k + 32); loadB(b1, yst, boff, k + 32);
    consume(a0, b0, acc);
    if (c + 2 < chunks){ loadA(a0, L, aoff, k + 64); loadB(b0, yst, boff, k + 64); }
    consume(a1, b1, acc);
    k += 64;
  }

  // cross-wave reduction (4 x 16KB LDS), then one fp32 partial write
  __shared__ float red[4][64 * 64];
  #pragma unroll
  for (int rt = 0; rt < 4; rt++)
    #pragma unroll
    for (int ct = 0; ct < 4; ct++)
      #pragma unroll
      for (int r = 0; r < 4; r++){
        int row = rt * 16 + q * 4 + r;
        int col = ct * 16 + m;
        red[w][row * 64 + col] = acc[rt][ct][r];
      }
  __syncthreads();
  float4* dst = (float4*)(part + (size_t)h * 16384 * 64 + (size_t)(growoff + m0) * 64);
  const float4* r0 = (const float4*)red[0];
  const float4* r1 = (const float4*)red[1];
  const float4* r2 = (const float4*)red[2];
  const float4* r3 = (const float4*)red[3];
  #pragma unroll
  for (int i = 0; i < 4; i++){
    int e = tid + i * 256;
    float4 s0 = r0[e], s1 = r1[e], s2 = r2[e], s3 = r3[e];
    float4 o;
    o.x = s0.x + s1.x + s2.x + s3.x;
    o.y = s0.y + s1.y + s2.y + s3.y;
    o.z = s0.z + s1.z + s2.z + s3.z;
    o.w = s0.w + s1.w + s2.w + s3.w;
    dst[e] = o;
  }
}

// ---------------------------------------------------------------------------
// epilogue: x[i][c] = relu(dinv[i] * (part0[i][c] + part1[i][c]))
// ---------------------------------------------------------------------------
__global__ __launch_bounds__(256) void epi_kernel(
    const float* __restrict__ part, const float* __restrict__ dinv,
    float* __restrict__ xbuf)
{
  int e4 = blockIdx.x * 256 + threadIdx.x;      // 262144 float4 groups
  const float4* p0 = (const float4*)part;
  const float4* p1 = (const float4*)(part + 16384 * 64);
  float4 v0 = p0[e4], v1 = p1[e4];
  float di = dinv[e4 >> 4];
  float4 o;
  o.x = fmaxf(di * (v0.x + v1.x), 0.f);
  o.y = fmaxf(di * (v0.y + v1.y), 0.f);
  o.z = fmaxf(di * (v0.z + v1.z), 0.f);
  o.w = fmaxf(di * (v0.w + v1.w), 0.f);
  ((float4*)xbuf)[e4] = o;
}

// ---------------------------------------------------------------------------
// pooling: pooled[r][seg][c] = sum_{i: bel_r[i]==seg} x[i][c]
// one wave per (rank, segment); deterministic order.
// ---------------------------------------------------------------------------
__global__ void pool_kernel(const float* __restrict__ xbuf,
                            const int* __restrict__ bel0,
                            const int* __restrict__ bel1,
                            const int* __restrict__ bel2,
                            float* __restrict__ pooled)
{
  int rb = blockIdx.x;                 // 0..191
  int r = rb >> 6, seg = rb & 63, lane = threadIdx.x;
  const int* bel; const float* x; int N;
  if (r == 0)      { bel = bel0; x = xbuf;               N = 4096; }
  else if (r == 1) { bel = bel1; x = xbuf + 4096 * 64;   N = 8192; }
  else             { bel = bel2; x = xbuf + 12288 * 64;  N = 4096; }
  float acc = 0.f;
  for (int i0 = 0; i0 < N; i0 += 64){
    int bv = bel[i0 + lane];
    unsigned long long mask = __ballot(bv == seg);
    while (mask){
      int idx = __builtin_ctzll(mask);
      mask &= mask - 1;
      acc += x[(size_t)(i0 + idx) * 64 + lane];
    }
  }
  pooled[rb * 64 + lane] = acc;
}

// ---------------------------------------------------------------------------
// readout: out[b][o] = sum_r ( pooled[r][b] @ Wr_r + br_r )[o]
// ---------------------------------------------------------------------------
__global__ __launch_bounds__(256) void readout_kernel(
    const float* __restrict__ pooled,
    const float* __restrict__ Wr0, const float* __restrict__ br0,
    const float* __restrict__ Wr1, const float* __restrict__ br1,
    const float* __restrict__ Wr2, const float* __restrict__ br2,
    float* __restrict__ out)
{
  int t = blockIdx.x * 256 + threadIdx.x;   // 2048 outputs
  int bseg = t >> 5, o = t & 31;
  float s = br0[o] + br1[o] + br2[o];
  const float* p0 = pooled + bseg * 64;
  const float* p1 = pooled + (64 + bseg) * 64;
  const float* p2 = pooled + (128 + bseg) * 64;
  for (int c = 0; c < 64; c++){
    s += p0[c] * Wr0[c * 32 + o];
    s += p1[c] * Wr1[c * 32 + o];
    s += p2[c] * Wr2[c * 32 + o];
  }
  out[t] = s;
}

// ---------------------------------------------------------------------------
extern "C" void kernel_launch(void* const* d_in, const int* in_sizes, int n_in,
                              void* d_out, int out_size, void* d_ws, size_t ws_size,
                              hipStream_t stream)
{
  const float* x0  = (const float*)d_in[0];
  const float* x1  = (const float*)d_in[1];
  const float* x2  = (const float*)d_in[2];
  const float* L0  = (const float*)d_in[3];
  const float* L1  = (const float*)d_in[4];
  const float* L2  = (const float*)d_in[5];
  const int*   bel0 = (const int*)d_in[6];
  const int*   bel1 = (const int*)d_in[7];
  const int*   bel2 = (const int*)d_in[8];
  const float* W0  = (const float*)d_in[9];
  const float* W1  = (const float*)d_in[10];
  const float* W2  = (const float*)d_in[11];
  const float* Wr0 = (const float*)d_in[12];
  const float* br0 = (const float*)d_in[13];
  const float* Wr1 = (const float*)d_in[14];
  const float* br1 = (const float*)d_in[15];
  const float* Wr2 = (const float*)d_in[16];
  const float* br2 = (const float*)d_in[17];

  // workspace layout (~14.4 MB total)
  float* dinv   = (float*)d_ws;                  // 16384 f32
  float* xbuf   = dinv + 16384;                  // 16384*64 f32 (4 MB)
  u16*   yst    = (u16*)(xbuf + 16384 * 64);     // 1,048,576 bf16 (2 MB)
  float* part   = (float*)(yst + 1048576);       // 2 * 16384*64 f32 (8 MB)
  float* pooled = part + 2 * 16384 * 64;         // 3*64*64 f32
  u16* yst0 = yst;
  u16* yst1 = yst + 64 * 4096;
  u16* yst2 = yst1 + 64 * 8192;

  rowsum_kernel<<<16384, 256, 0, stream>>>(L0, L1, L2, dinv);
  for (int layer = 0; layer < 2; layer++){
    xw_kernel<<<256, 256, 0, stream>>>(x0, x1, x2, xbuf, W0, W1, W2, layer,
                                       dinv, yst0, yst1, yst2);
    gemm_kernel<<<512, 256, 0, stream>>>(L0, L1, L2, yst0, yst1, yst2, part);
    epi_kernel<<<1024, 256, 0, stream>>>(part, dinv, xbuf);
  }
  pool_kernel<<<192, 64, 0, stream>>>(xbuf, bel0, bel1, bel2, pooled);
  readout_kernel<<<8, 256, 0, stream>>>(pooled, Wr0, br0, Wr1, br1, Wr2, br2,
                                        (float*)d_out);
}

// Round 2
// 664.463 us; speedup vs baseline: 1.1110x; 1.1110x over previous
//
#include <hip/hip_runtime.h>

typedef unsigned short u16;
using floatx4 = __attribute__((ext_vector_type(4))) float;
using short8  = __attribute__((ext_vector_type(8))) short;

__device__ __forceinline__ u16 f2bf(float f){
  unsigned int u = __float_as_uint(f);
  u += 0x7fffu + ((u >> 16) & 1u);   // round-to-nearest-even
  return (u16)(u >> 16);
}

// ---------------------------------------------------------------------------
// conv_rowsum: one pass over fp32 L (402 MB read):
//   - writes bf16 copy lb (201 MB)  [unscaled; dinv folded downstream]
//   - dinv[row] = d!=0 ? rsqrt(sum_j |L[row][j]|) : 0
// rows 0..4095 -> L0, 4096..12287 -> L1, 12288..16383 -> L2
// ---------------------------------------------------------------------------
__global__ __launch_bounds__(256) void conv_rowsum_kernel(
    const float* __restrict__ L0, const float* __restrict__ L1,
    const float* __restrict__ L2, u16* __restrict__ lb,
    float* __restrict__ dinv)
{
  int row = blockIdx.x;
  const float* L; int N; size_t doff;
  if (row < 4096)       { L = L0 + (size_t)row * 4096;          N = 4096; doff = (size_t)row * 4096; }
  else if (row < 12288) { int r = row - 4096;
                          L = L1 + (size_t)r * 8192;            N = 8192; doff = 16777216u + (size_t)r * 8192; }
  else                  { int r = row - 12288;
                          L = L2 + (size_t)r * 4096;            N = 4096; doff = 83886080u + (size_t)r * 4096; }
  u16* dst = lb + doff;
  float s = 0.f;
  for (int i = threadIdx.x * 4; i < N; i += 1024){
    float4 v = *(const float4*)(L + i);
    s += fabsf(v.x) + fabsf(v.y) + fabsf(v.z) + fabsf(v.w);
    ushort4 o;
    o.x = f2bf(v.x); o.y = f2bf(v.y); o.z = f2bf(v.z); o.w = f2bf(v.w);
    *(ushort4*)(dst + i) = o;
  }
  #pragma unroll
  for (int off = 32; off > 0; off >>= 1) s += __shfl_down(s, off);
  __shared__ float wsum[4];
  if ((threadIdx.x & 63) == 0) wsum[threadIdx.x >> 6] = s;
  __syncthreads();
  if (threadIdx.x == 0){
    float d = wsum[0] + wsum[1] + wsum[2] + wsum[3];
    dinv[row] = (d != 0.f) ? rsqrtf(d) : 0.f;
  }
}

// ---------------------------------------------------------------------------
// xw: Yst[c][j] = bf16( dinv[j] * (x @ W_layer)[j][c] )  -- TRANSPOSED output
// One block = 64 rows of one rank. MFMA 16x16x32 on LDS-staged bf16 tiles.
// ---------------------------------------------------------------------------
__global__ __launch_bounds__(256) void xw_kernel(
    const float* __restrict__ x0, const float* __restrict__ x1,
    const float* __restrict__ x2, const float* __restrict__ xbuf,
    const float* __restrict__ W0c, const float* __restrict__ W1c,
    const float* __restrict__ W2c, int layer,
    const float* __restrict__ dinv,
    u16* __restrict__ yst0, u16* __restrict__ yst1, u16* __restrict__ yst2)
{
  int grow0 = blockIdx.x * 64;         // global row base (0..16383)
  int lrow0, N; const float* xin; const float* W; u16* yst;
  if (grow0 < 4096)       { lrow0 = grow0;         N = 4096; W = W0c; yst = yst0; xin = x0; }
  else if (grow0 < 12288) { lrow0 = grow0 - 4096;  N = 8192; W = W1c; yst = yst1; xin = x1; }
  else                    { lrow0 = grow0 - 12288; N = 4096; W = W2c; yst = yst2; xin = x2; }
  const float* xsrc = layer ? (xbuf + (size_t)grow0 * 64) : (xin + (size_t)lrow0 * 64);
  W += layer * 4096;

  __shared__ u16 xt[64 * 72];   // xt[j][k], stride 72 pad
  __shared__ u16 wt[64 * 72];   // wt[c][k] = W[k][c] (transposed)

  int tid = threadIdx.x;
  {
    int j  = tid >> 2;
    int c0 = (tid & 3) * 16;
    const float* src = xsrc + j * 64 + c0;
    #pragma unroll
    for (int i = 0; i < 4; i++){
      float4 v = *(const float4*)(src + i * 4);
      int o = j * 72 + c0 + i * 4;
      xt[o + 0] = f2bf(v.x); xt[o + 1] = f2bf(v.y);
      xt[o + 2] = f2bf(v.z); xt[o + 3] = f2bf(v.w);
    }
    const float* wsrc = W + j * 64 + c0;   // j doubles as k-index for W staging
    #pragma unroll
    for (int i = 0; i < 4; i++){
      float4 v = *(const float4*)(wsrc + i * 4);
      int c = c0 + i * 4;
      wt[(c + 0) * 72 + j] = f2bf(v.x);
      wt[(c + 1) * 72 + j] = f2bf(v.y);
      wt[(c + 2) * 72 + j] = f2bf(v.z);
      wt[(c + 3) * 72 + j] = f2bf(v.w);
    }
  }
  __syncthreads();

  int lane = tid & 63, w = tid >> 6;
  int m = lane & 15, q = lane >> 4;
  floatx4 acc[4] = {};
  #pragma unroll
  for (int kk = 0; kk < 2; kk++){
    short8 af = *(const short8*)(&xt[(w * 16 + m) * 72 + kk * 32 + q * 8]);
    #pragma unroll
    for (int ct = 0; ct < 4; ct++){
      short8 bf = *(const short8*)(&wt[(ct * 16 + m) * 72 + kk * 32 + q * 8]);
      acc[ct] = __builtin_amdgcn_mfma_f32_16x16x32_bf16(af, bf, acc[ct], 0, 0, 0);
    }
  }
  // C layout: row(j) = q*4+r (+w*16), col(c) = m (+ct*16)   [m89-verified]
  #pragma unroll
  for (int r = 0; r < 4; r++){
    int j = w * 16 + q * 4 + r;
    float di = dinv[grow0 + j];
    #pragma unroll
    for (int ct = 0; ct < 4; ct++){
      int c = ct * 16 + m;
      yst[(size_t)c * N + lrow0 + j] = f2bf(acc[ct][r] * di);
    }
  }
}

// ---------------------------------------------------------------------------
// Big GEMM on bf16 L: part[h][i][c] = sum_{k in half h} lb[i][k] * Yst[c][k]
// 512 blocks: rank0 [0,128), rank1 [128,384), rank2 [384,512).
// Block = (mblock, khalf h): 64 rows x 64 cols; 4 waves split the K-half
// 4-way, LDS-reduce, write one fp32 partial. A/B direct global->reg bf16.
// ---------------------------------------------------------------------------
struct Stage { short8 a[4]; short8 b[4]; };

__device__ __forceinline__ void loadS(Stage& s, const u16* __restrict__ lb,
                                      const u16* __restrict__ yst,
                                      const int aoff[4], const int boff[4], int k){
  #pragma unroll
  for (int rt = 0; rt < 4; rt++) s.a[rt] = *(const short8*)(lb + aoff[rt] + k);
  #pragma unroll
  for (int ct = 0; ct < 4; ct++) s.b[ct] = *(const short8*)(yst + boff[ct] + k);
}
__device__ __forceinline__ void consume(const Stage& s, floatx4 acc[4][4]){
  #pragma unroll
  for (int rt = 0; rt < 4; rt++)
    #pragma unroll
    for (int ct = 0; ct < 4; ct++)
      acc[rt][ct] = __builtin_amdgcn_mfma_f32_16x16x32_bf16(s.a[rt], s.b[ct],
                                                            acc[rt][ct], 0, 0, 0);
}

__global__ __launch_bounds__(256, 2) void gemm_kernel(
    const u16* __restrict__ lb,
    const u16* __restrict__ yst0, const u16* __restrict__ yst1,
    const u16* __restrict__ yst2, float* __restrict__ part)
{
  int b = blockIdx.x;
  const u16* A; const u16* yst; int N, growoff, mb, h;
  if (b < 128)      { A = lb;             yst = yst0; N = 4096; growoff = 0;     mb = b >> 1;         h = b & 1; }
  else if (b < 384) { A = lb + 16777216u; yst = yst1; N = 8192; growoff = 4096;  mb = (b - 128) >> 1; h = b & 1; }
  else              { A = lb + 83886080u; yst = yst2; N = 4096; growoff = 12288; mb = (b - 384) >> 1; h = b & 1; }
  int m0 = mb * 64;
  int tid = threadIdx.x, lane = tid & 63, w = tid >> 6;
  int m = lane & 15, q = lane >> 4;
  int kstart = h * (N >> 1) + w * (N >> 3);
  int chunks = N >> 8;               // per-wave chunks of 32 (16 or 32, even)

  int aoff[4], boff[4];
  #pragma unroll
  for (int rt = 0; rt < 4; rt++) aoff[rt] = (m0 + rt * 16 + m) * N + q * 8;
  #pragma unroll
  for (int ct = 0; ct < 4; ct++) boff[ct] = (ct * 16 + m) * N + q * 8;

  floatx4 acc[4][4] = {};
  int k = kstart;
  Stage s0, s1;
  loadS(s0, A, yst, aoff, boff, k);
  for (int c = 0; c < chunks; c += 2){
    loadS(s1, A, yst, aoff, boff, k + 32);
    consume(s0, acc);
    if (c + 2 < chunks) loadS(s0, A, yst, aoff, boff, k + 64);
    consume(s1, acc);
    k += 64;
  }

  // cross-wave reduction (4 x 16KB LDS), then one fp32 partial write
  __shared__ float red[4][64 * 64];
  #pragma unroll
  for (int rt = 0; rt < 4; rt++)
    #pragma unroll
    for (int ct = 0; ct < 4; ct++)
      #pragma unroll
      for (int r = 0; r < 4; r++){
        int row = rt * 16 + q * 4 + r;
        int col = ct * 16 + m;
        red[w][row * 64 + col] = acc[rt][ct][r];
      }
  __syncthreads();
  float4* dst = (float4*)(part + (size_t)h * 16384 * 64 + (size_t)(growoff + m0) * 64);
  const float4* r0 = (const float4*)red[0];
  const float4* r1 = (const float4*)red[1];
  const float4* r2 = (const float4*)red[2];
  const float4* r3 = (const float4*)red[3];
  #pragma unroll
  for (int i = 0; i < 4; i++){
    int e = tid + i * 256;
    float4 v0 = r0[e], v1 = r1[e], v2 = r2[e], v3 = r3[e];
    float4 o;
    o.x = v0.x + v1.x + v2.x + v3.x;
    o.y = v0.y + v1.y + v2.y + v3.y;
    o.z = v0.z + v1.z + v2.z + v3.z;
    o.w = v0.w + v1.w + v2.w + v3.w;
    dst[e] = o;
  }
}

// ---------------------------------------------------------------------------
// epilogue: x[i][c] = relu(dinv[i] * (part0[i][c] + part1[i][c]))
// ---------------------------------------------------------------------------
__global__ __launch_bounds__(256) void epi_kernel(
    const float* __restrict__ part, const float* __restrict__ dinv,
    float* __restrict__ xbuf)
{
  int e4 = blockIdx.x * 256 + threadIdx.x;      // 262144 float4 groups
  const float4* p0 = (const float4*)part;
  const float4* p1 = (const float4*)(part + 16384 * 64);
  float4 v0 = p0[e4], v1 = p1[e4];
  float di = dinv[e4 >> 4];
  float4 o;
  o.x = fmaxf(di * (v0.x + v1.x), 0.f);
  o.y = fmaxf(di * (v0.y + v1.y), 0.f);
  o.z = fmaxf(di * (v0.z + v1.z), 0.f);
  o.w = fmaxf(di * (v0.w + v1.w), 0.f);
  ((float4*)xbuf)[e4] = o;
}

// ---------------------------------------------------------------------------
// pooling: pooled[r][seg][c] = sum_{i: bel_r[i]==seg} x[i][c]
// one block (4 waves) per (rank, segment); waves split rows, LDS combine.
// ---------------------------------------------------------------------------
__global__ __launch_bounds__(256) void pool_kernel(
    const float* __restrict__ xbuf,
    const int* __restrict__ bel0, const int* __restrict__ bel1,
    const int* __restrict__ bel2, float* __restrict__ pooled)
{
  int rb = blockIdx.x;                 // 0..191
  int r = rb >> 6, seg = rb & 63;
  int lane = threadIdx.x & 63, w = threadIdx.x >> 6;
  const int* bel; const float* x; int N;
  if (r == 0)      { bel = bel0; x = xbuf;               N = 4096; }
  else if (r == 1) { bel = bel1; x = xbuf + 4096 * 64;   N = 8192; }
  else             { bel = bel2; x = xbuf + 12288 * 64;  N = 4096; }
  float acc = 0.f;
  for (int i0 = w * 64; i0 < N; i0 += 256){
    int bv = bel[i0 + lane];
    unsigned long long mask = __ballot(bv == seg);
    while (mask){
      int idx = __builtin_ctzll(mask);
      mask &= mask - 1;
      acc += x[(size_t)(i0 + idx) * 64 + lane];
    }
  }
  __shared__ float red[4][64];
  red[w][lane] = acc;
  __syncthreads();
  if (w == 0)
    pooled[rb * 64 + lane] = red[0][lane] + red[1][lane] + red[2][lane] + red[3][lane];
}

// ---------------------------------------------------------------------------
// readout: out[b][o] = sum_r ( pooled[r][b] @ Wr_r + br_r )[o]
// ---------------------------------------------------------------------------
__global__ __launch_bounds__(256) void readout_kernel(
    const float* __restrict__ pooled,
    const float* __restrict__ Wr0, const float* __restrict__ br0,
    const float* __restrict__ Wr1, const float* __restrict__ br1,
    const float* __restrict__ Wr2, const float* __restrict__ br2,
    float* __restrict__ out)
{
  int t = blockIdx.x * 256 + threadIdx.x;   // 2048 outputs
  int bseg = t >> 5, o = t & 31;
  float s = br0[o] + br1[o] + br2[o];
  const float* p0 = pooled + bseg * 64;
  const float* p1 = pooled + (64 + bseg) * 64;
  const float* p2 = pooled + (128 + bseg) * 64;
  for (int c = 0; c < 64; c++){
    s += p0[c] * Wr0[c * 32 + o];
    s += p1[c] * Wr1[c * 32 + o];
    s += p2[c] * Wr2[c * 32 + o];
  }
  out[t] = s;
}

// ---------------------------------------------------------------------------
extern "C" void kernel_launch(void* const* d_in, const int* in_sizes, int n_in,
                              void* d_out, int out_size, void* d_ws, size_t ws_size,
                              hipStream_t stream)
{
  const float* x0  = (const float*)d_in[0];
  const float* x1  = (const float*)d_in[1];
  const float* x2  = (const float*)d_in[2];
  const float* L0  = (const float*)d_in[3];
  const float* L1  = (const float*)d_in[4];
  const float* L2  = (const float*)d_in[5];
  const int*   bel0 = (const int*)d_in[6];
  const int*   bel1 = (const int*)d_in[7];
  const int*   bel2 = (const int*)d_in[8];
  const float* W0  = (const float*)d_in[9];
  const float* W1  = (const float*)d_in[10];
  const float* W2  = (const float*)d_in[11];
  const float* Wr0 = (const float*)d_in[12];
  const float* br0 = (const float*)d_in[13];
  const float* Wr1 = (const float*)d_in[14];
  const float* br1 = (const float*)d_in[15];
  const float* Wr2 = (const float*)d_in[16];
  const float* br2 = (const float*)d_in[17];

  // workspace layout (~216 MB; ws is ~1 GB per harness fill size)
  float* dinv   = (float*)d_ws;                  // 16384 f32
  float* xbuf   = dinv + 16384;                  // 16384*64 f32 (4 MB)
  float* part   = xbuf + 1048576;                // 2*16384*64 f32 (8 MB)
  float* pooled = part + 2097152;                // 3*64*64 f32
  u16*   yst    = (u16*)(pooled + 12288);        // 1,048,576 bf16 (2 MB)
  u16*   lb     = yst + 1048576;                 // 100,663,296 bf16 (201 MB)
  u16* yst0 = yst;
  u16* yst1 = yst + 64 * 4096;
  u16* yst2 = yst1 + 64 * 8192;

  conv_rowsum_kernel<<<16384, 256, 0, stream>>>(L0, L1, L2, lb, dinv);
  for (int layer = 0; layer < 2; layer++){
    xw_kernel<<<256, 256, 0, stream>>>(x0, x1, x2, xbuf, W0, W1, W2, layer,
                                       dinv, yst0, yst1, yst2);
    gemm_kernel<<<512, 256, 0, stream>>>(lb, yst0, yst1, yst2, part);
    epi_kernel<<<1024, 256, 0, stream>>>(part, dinv, xbuf);
  }
  pool_kernel<<<192, 256, 0, stream>>>(xbuf, bel0, bel1, bel2, pooled);
  readout_kernel<<<8, 256, 0, stream>>>(pooled, Wr0, br0, Wr1, br1, Wr2, br2,
                                        (float*)d_out);
}

// Round 3
// 624.681 us; speedup vs baseline: 1.1817x; 1.0637x over previous
//
#include <hip/hip_runtime.h>

typedef unsigned short u16;
using floatx4 = __attribute__((ext_vector_type(4))) float;
using short8  = __attribute__((ext_vector_type(8))) short;

__device__ __forceinline__ u16 f2bf(float f){
  unsigned int u = __float_as_uint(f);
  u += 0x7fffu + ((u >> 16) & 1u);   // round-to-nearest-even
  return (u16)(u >> 16);
}

// ---------------------------------------------------------------------------
// conv_rowsum: one WAVE per row (no LDS, no barriers):
//   - writes bf16 copy lb (201 MB)
//   - dinv[row] = d!=0 ? rsqrt(sum_j |L[row][j]|) : 0
// rows 0..4095 -> L0, 4096..12287 -> L1, 12288..16383 -> L2
// ---------------------------------------------------------------------------
__global__ __launch_bounds__(256) void conv_rowsum_kernel(
    const float* __restrict__ L0, const float* __restrict__ L1,
    const float* __restrict__ L2, u16* __restrict__ lb,
    float* __restrict__ dinv)
{
  int row  = blockIdx.x * 4 + (threadIdx.x >> 6);
  int lane = threadIdx.x & 63;
  const float* L; int N; size_t doff;
  if (row < 4096)       { L = L0 + (size_t)row * 4096;  N = 4096; doff = (size_t)row * 4096; }
  else if (row < 12288) { int r = row - 4096;
                          L = L1 + (size_t)r * 8192;    N = 8192; doff = 16777216u + (size_t)r * 8192; }
  else                  { int r = row - 12288;
                          L = L2 + (size_t)r * 4096;    N = 4096; doff = 83886080u + (size_t)r * 4096; }
  u16* dst = lb + doff;
  float s = 0.f;
  for (int i = lane * 4; i < N; i += 256){
    float4 v = *(const float4*)(L + i);
    s += fabsf(v.x) + fabsf(v.y) + fabsf(v.z) + fabsf(v.w);
    ushort4 o;
    o.x = f2bf(v.x); o.y = f2bf(v.y); o.z = f2bf(v.z); o.w = f2bf(v.w);
    *(ushort4*)(dst + i) = o;
  }
  #pragma unroll
  for (int off = 32; off > 0; off >>= 1) s += __shfl_down(s, off);
  if (lane == 0) dinv[row] = (s != 0.f) ? rsqrtf(s) : 0.f;
}

// ---------------------------------------------------------------------------
// xw: Yst[c][j] = bf16( dinv[j] * (x @ W_layer)[j][c] )  -- TRANSPOSED output
// ---------------------------------------------------------------------------
__global__ __launch_bounds__(256) void xw_kernel(
    const float* __restrict__ x0, const float* __restrict__ x1,
    const float* __restrict__ x2, const float* __restrict__ xbuf,
    const float* __restrict__ W0c, const float* __restrict__ W1c,
    const float* __restrict__ W2c, int layer,
    const float* __restrict__ dinv,
    u16* __restrict__ yst0, u16* __restrict__ yst1, u16* __restrict__ yst2)
{
  int grow0 = blockIdx.x * 64;         // global row base (0..16383)
  int lrow0, N; const float* xin; const float* W; u16* yst;
  if (grow0 < 4096)       { lrow0 = grow0;         N = 4096; W = W0c; yst = yst0; xin = x0; }
  else if (grow0 < 12288) { lrow0 = grow0 - 4096;  N = 8192; W = W1c; yst = yst1; xin = x1; }
  else                    { lrow0 = grow0 - 12288; N = 4096; W = W2c; yst = yst2; xin = x2; }
  const float* xsrc = layer ? (xbuf + (size_t)grow0 * 64) : (xin + (size_t)lrow0 * 64);
  W += layer * 4096;

  __shared__ u16 xt[64 * 72];   // xt[j][k], stride 72 pad
  __shared__ u16 wt[64 * 72];   // wt[c][k] = W[k][c] (transposed)

  int tid = threadIdx.x;
  {
    int j  = tid >> 2;
    int c0 = (tid & 3) * 16;
    const float* src = xsrc + j * 64 + c0;
    #pragma unroll
    for (int i = 0; i < 4; i++){
      float4 v = *(const float4*)(src + i * 4);
      int o = j * 72 + c0 + i * 4;
      xt[o + 0] = f2bf(v.x); xt[o + 1] = f2bf(v.y);
      xt[o + 2] = f2bf(v.z); xt[o + 3] = f2bf(v.w);
    }
    const float* wsrc = W + j * 64 + c0;   // j doubles as k-index for W staging
    #pragma unroll
    for (int i = 0; i < 4; i++){
      float4 v = *(const float4*)(wsrc + i * 4);
      int c = c0 + i * 4;
      wt[(c + 0) * 72 + j] = f2bf(v.x);
      wt[(c + 1) * 72 + j] = f2bf(v.y);
      wt[(c + 2) * 72 + j] = f2bf(v.z);
      wt[(c + 3) * 72 + j] = f2bf(v.w);
    }
  }
  __syncthreads();

  int lane = tid & 63, w = tid >> 6;
  int m = lane & 15, q = lane >> 4;
  floatx4 acc[4] = {};
  #pragma unroll
  for (int kk = 0; kk < 2; kk++){
    short8 af = *(const short8*)(&xt[(w * 16 + m) * 72 + kk * 32 + q * 8]);
    #pragma unroll
    for (int ct = 0; ct < 4; ct++){
      short8 bf = *(const short8*)(&wt[(ct * 16 + m) * 72 + kk * 32 + q * 8]);
      acc[ct] = __builtin_amdgcn_mfma_f32_16x16x32_bf16(af, bf, acc[ct], 0, 0, 0);
    }
  }
  // C layout: row(j) = q*4+r (+w*16), col(c) = m (+ct*16)   [m89-verified]
  #pragma unroll
  for (int r = 0; r < 4; r++){
    int j = w * 16 + q * 4 + r;
    float di = dinv[grow0 + j];
    #pragma unroll
    for (int ct = 0; ct < 4; ct++){
      int c = ct * 16 + m;
      yst[(size_t)c * N + lrow0 + j] = f2bf(acc[ct][r] * di);
    }
  }
}

// ---------------------------------------------------------------------------
// Big GEMM on bf16 L: part[h][i][c] = sum_{k in half h} lb[i][k] * Yst[c][k]
// 512 blocks: rank0 [0,128), rank1 [128,384), rank2 [384,512).
// Block = (mblock, khalf h): 64 rows x 64 cols; 4 waves split the K-half
// 4-way. A path: full-128B-line global loads -> regs -> wave-private LDS
// tile (pad-72) -> ds_read_b128 fragments. No barriers in the K loop.
// B (yst, L2-resident) direct global->reg, register double-buffered.
// ---------------------------------------------------------------------------
struct BStage { short8 b[4]; };

__device__ __forceinline__ void loadB(BStage& s, const u16* __restrict__ yst,
                                      const int boff[4], int k){
  #pragma unroll
  for (int ct = 0; ct < 4; ct++)
    s.b[ct] = *(const short8*)(yst + boff[ct] + k);
}
__device__ __forceinline__ void loadAG(short8 G[8], const u16* __restrict__ A,
                                       size_t abase, int N){
  #pragma unroll
  for (int rr = 0; rr < 8; rr++)
    G[rr] = *(const short8*)(A + abase + (size_t)rr * 8 * N);
}
__device__ __forceinline__ void writeTile(u16* tp, const short8 G[8]){
  #pragma unroll
  for (int rr = 0; rr < 8; rr++)
    *(short8*)(tp + rr * 8 * 72) = G[rr];
}

__global__ __launch_bounds__(256, 2) void gemm_kernel(
    const u16* __restrict__ lb,
    const u16* __restrict__ yst0, const u16* __restrict__ yst1,
    const u16* __restrict__ yst2, float* __restrict__ part)
{
  int b = blockIdx.x;
  const u16* A; const u16* yst; int N, growoff, mb, h;
  if (b < 128)      { A = lb;             yst = yst0; N = 4096; growoff = 0;     mb = b >> 1;         h = b & 1; }
  else if (b < 384) { A = lb + 16777216u; yst = yst1; N = 8192; growoff = 4096;  mb = (b - 128) >> 1; h = b & 1; }
  else              { A = lb + 83886080u; yst = yst2; N = 4096; growoff = 12288; mb = (b - 384) >> 1; h = b & 1; }
  int m0 = mb * 64;
  int tid = threadIdx.x, lane = tid & 63, w = tid >> 6;
  int m = lane & 15, q = lane >> 4;
  int kstart = h * (N >> 1) + w * (N >> 3);
  int T = N >> 9;                     // 64-k tiles per wave (8 or 16)

  // 64 KB shared: during K-loop = 4 wave-private A tiles (36 KB used);
  // after a barrier, reused as the 4x(64x64) fp32 reduction buffer.
  __shared__ char shraw[65536];
  u16* atile = (u16*)shraw;
  u16* myt = atile + w * 4608;                      // [64][72] bf16
  u16* tp  = myt + (lane >> 3) * 72 + (lane & 7) * 8;

  int boff[4];
  #pragma unroll
  for (int ct = 0; ct < 4; ct++) boff[ct] = (ct * 16 + m) * N + q * 8;
  size_t abase = (size_t)(m0 + (lane >> 3)) * N + kstart + (lane & 7) * 8;

  floatx4 acc[4][4] = {};
  short8 G[8]; BStage b0, b1, nb0, nb1;
  loadAG(G, A, abase, N);
  loadB(b0, yst, boff, kstart);
  loadB(b1, yst, boff, kstart + 32);
  writeTile(tp, G);                                  // waits on G only
  int kbase = kstart;
  for (int t = 0; t < T; t++){
    bool more = (t + 1 < T);
    if (more){
      loadAG(G, A, abase + 64, N);
      loadB(nb0, yst, boff, kbase + 64);
      loadB(nb1, yst, boff, kbase + 96);
    }
    #pragma unroll
    for (int kk = 0; kk < 2; kk++){
      short8 a[4];
      #pragma unroll
      for (int rt = 0; rt < 4; rt++)
        a[rt] = *(const short8*)(myt + (rt * 16 + m) * 72 + kk * 32 + q * 8);
      const BStage& bb = kk ? b1 : b0;
      #pragma unroll
      for (int rt = 0; rt < 4; rt++)
        #pragma unroll
        for (int ct = 0; ct < 4; ct++)
          acc[rt][ct] = __builtin_amdgcn_mfma_f32_16x16x32_bf16(a[rt], bb.b[ct],
                                                                acc[rt][ct], 0, 0, 0);
    }
    if (more){
      writeTile(tp, G);     // same-wave DS ordering: reads above retire first
      b0 = nb0; b1 = nb1;
      abase += 64; kbase += 64;
    }
  }

  // cross-wave reduction: reuse shraw as red[4][64*64] fp32
  __syncthreads();                                   // all frag reads done
  float* red = (float*)shraw;
  #pragma unroll
  for (int rt = 0; rt < 4; rt++)
    #pragma unroll
    for (int ct = 0; ct < 4; ct++)
      #pragma unroll
      for (int r = 0; r < 4; r++){
        int row = rt * 16 + q * 4 + r;
        int col = ct * 16 + m;
        red[w * 4096 + row * 64 + col] = acc[rt][ct][r];
      }
  __syncthreads();
  float4* dst = (float4*)(part + (size_t)h * 16384 * 64 + (size_t)(growoff + m0) * 64);
  const float4* r0 = (const float4*)(red);
  const float4* r1 = (const float4*)(red + 4096);
  const float4* r2 = (const float4*)(red + 8192);
  const float4* r3 = (const float4*)(red + 12288);
  #pragma unroll
  for (int i = 0; i < 4; i++){
    int e = tid + i * 256;
    float4 v0 = r0[e], v1 = r1[e], v2 = r2[e], v3 = r3[e];
    float4 o;
    o.x = v0.x + v1.x + v2.x + v3.x;
    o.y = v0.y + v1.y + v2.y + v3.y;
    o.z = v0.z + v1.z + v2.z + v3.z;
    o.w = v0.w + v1.w + v2.w + v3.w;
    dst[e] = o;
  }
}

// ---------------------------------------------------------------------------
// epilogue: x[i][c] = relu(dinv[i] * (part0[i][c] + part1[i][c]))
// ---------------------------------------------------------------------------
__global__ __launch_bounds__(256) void epi_kernel(
    const float* __restrict__ part, const float* __restrict__ dinv,
    float* __restrict__ xbuf)
{
  int e4 = blockIdx.x * 256 + threadIdx.x;      // 262144 float4 groups
  const float4* p0 = (const float4*)part;
  const float4* p1 = (const float4*)(part + 16384 * 64);
  float4 v0 = p0[e4], v1 = p1[e4];
  float di = dinv[e4 >> 4];
  float4 o;
  o.x = fmaxf(di * (v0.x + v1.x), 0.f);
  o.y = fmaxf(di * (v0.y + v1.y), 0.f);
  o.z = fmaxf(di * (v0.z + v1.z), 0.f);
  o.w = fmaxf(di * (v0.w + v1.w), 0.f);
  ((float4*)xbuf)[e4] = o;
}

// ---------------------------------------------------------------------------
// pooling: pooled[r][seg][c] = sum_{i: bel_r[i]==seg} x[i][c]
// ---------------------------------------------------------------------------
__global__ __launch_bounds__(256) void pool_kernel(
    const float* __restrict__ xbuf,
    const int* __restrict__ bel0, const int* __restrict__ bel1,
    const int* __restrict__ bel2, float* __restrict__ pooled)
{
  int rb = blockIdx.x;                 // 0..191
  int r = rb >> 6, seg = rb & 63;
  int lane = threadIdx.x & 63, w = threadIdx.x >> 6;
  const int* bel; const float* x; int N;
  if (r == 0)      { bel = bel0; x = xbuf;               N = 4096; }
  else if (r == 1) { bel = bel1; x = xbuf + 4096 * 64;   N = 8192; }
  else             { bel = bel2; x = xbuf + 12288 * 64;  N = 4096; }
  float acc = 0.f;
  for (int i0 = w * 64; i0 < N; i0 += 256){
    int bv = bel[i0 + lane];
    unsigned long long mask = __ballot(bv == seg);
    while (mask){
      int idx = __builtin_ctzll(mask);
      mask &= mask - 1;
      acc += x[(size_t)(i0 + idx) * 64 + lane];
    }
  }
  __shared__ float red[4][64];
  red[w][lane] = acc;
  __syncthreads();
  if (w == 0)
    pooled[rb * 64 + lane] = red[0][lane] + red[1][lane] + red[2][lane] + red[3][lane];
}

// ---------------------------------------------------------------------------
// readout: out[b][o] = sum_r ( pooled[r][b] @ Wr_r + br_r )[o]
// ---------------------------------------------------------------------------
__global__ __launch_bounds__(256) void readout_kernel(
    const float* __restrict__ pooled,
    const float* __restrict__ Wr0, const float* __restrict__ br0,
    const float* __restrict__ Wr1, const float* __restrict__ br1,
    const float* __restrict__ Wr2, const float* __restrict__ br2,
    float* __restrict__ out)
{
  int t = blockIdx.x * 256 + threadIdx.x;   // 2048 outputs
  int bseg = t >> 5, o = t & 31;
  float s = br0[o] + br1[o] + br2[o];
  const float* p0 = pooled + bseg * 64;
  const float* p1 = pooled + (64 + bseg) * 64;
  const float* p2 = pooled + (128 + bseg) * 64;
  for (int c = 0; c < 64; c++){
    s += p0[c] * Wr0[c * 32 + o];
    s += p1[c] * Wr1[c * 32 + o];
    s += p2[c] * Wr2[c * 32 + o];
  }
  out[t] = s;
}

// ---------------------------------------------------------------------------
extern "C" void kernel_launch(void* const* d_in, const int* in_sizes, int n_in,
                              void* d_out, int out_size, void* d_ws, size_t ws_size,
                              hipStream_t stream)
{
  const float* x0  = (const float*)d_in[0];
  const float* x1  = (const float*)d_in[1];
  const float* x2  = (const float*)d_in[2];
  const float* L0  = (const float*)d_in[3];
  const float* L1  = (const float*)d_in[4];
  const float* L2  = (const float*)d_in[5];
  const int*   bel0 = (const int*)d_in[6];
  const int*   bel1 = (const int*)d_in[7];
  const int*   bel2 = (const int*)d_in[8];
  const float* W0  = (const float*)d_in[9];
  const float* W1  = (const float*)d_in[10];
  const float* W2  = (const float*)d_in[11];
  const float* Wr0 = (const float*)d_in[12];
  const float* br0 = (const float*)d_in[13];
  const float* Wr1 = (const float*)d_in[14];
  const float* br1 = (const float*)d_in[15];
  const float* Wr2 = (const float*)d_in[16];
  const float* br2 = (const float*)d_in[17];

  // workspace layout (~216 MB; ws is ~1 GB per harness fill size)
  float* dinv   = (float*)d_ws;                  // 16384 f32
  float* xbuf   = dinv + 16384;                  // 16384*64 f32 (4 MB)
  float* part   = xbuf + 1048576;                // 2*16384*64 f32 (8 MB)
  float* pooled = part + 2097152;                // 3*64*64 f32
  u16*   yst    = (u16*)(pooled + 12288);        // 1,048,576 bf16 (2 MB)
  u16*   lb     = yst + 1048576;                 // 100,663,296 bf16 (201 MB)
  u16* yst0 = yst;
  u16* yst1 = yst + 64 * 4096;
  u16* yst2 = yst1 + 64 * 8192;

  conv_rowsum_kernel<<<4096, 256, 0, stream>>>(L0, L1, L2, lb, dinv);
  for (int layer = 0; layer < 2; layer++){
    xw_kernel<<<256, 256, 0, stream>>>(x0, x1, x2, xbuf, W0, W1, W2, layer,
                                       dinv, yst0, yst1, yst2);
    gemm_kernel<<<512, 256, 0, stream>>>(lb, yst0, yst1, yst2, part);
    epi_kernel<<<1024, 256, 0, stream>>>(part, dinv, xbuf);
  }
  pool_kernel<<<192, 256, 0, stream>>>(xbuf, bel0, bel1, bel2, pooled);
  readout_kernel<<<8, 256, 0, stream>>>(pooled, Wr0, br0, Wr1, br1, Wr2, br2,
                                        (float*)d_out);
}